// Round 1
// baseline (361.744 us; speedup 1.0000x reference)
//
#include <hip/hip_runtime.h>
#include <cstdint>

typedef unsigned short u16;   // bf16 bit pattern
typedef unsigned int   u32;
typedef __attribute__((ext_vector_type(8))) __bf16 bf16x8;
typedef __attribute__((ext_vector_type(2))) float  f32x2;
typedef __attribute__((ext_vector_type(4))) float  f32x4;
typedef __attribute__((ext_vector_type(4))) u32    u32x4;

#define N_IMG 4
#define C_DIM 256
#define H_DIM 128
#define W_DIM 128
#define HW    (H_DIM * W_DIM)      // 16384
#define M_TOT (N_IMG * HW)         // 65536
#define CG    64
#define PADOFF 112
#define EPSV  1e-5f

__device__ __forceinline__ u16 f2b(float f) {
  u32 u = __float_as_uint(f);
  u += 0x7fffu + ((u >> 16) & 1u);   // round-to-nearest-even
  return (u16)(u >> 16);
}

// async global->LDS, 16B per lane; LDS dest = wave-uniform base + lane*16
__device__ __forceinline__ void async_cp16(const void* g, void* l) {
  __builtin_amdgcn_global_load_lds(
      (const __attribute__((address_space(1))) void*)g,
      (__attribute__((address_space(3))) void*)l, 16, 0, 0);
}

// cast n f32 -> n bf16, 4 elems/thread
__global__ __launch_bounds__(256) void cast_w(const float* __restrict__ in,
                                              u16* __restrict__ out, int n4) {
  int i = blockIdx.x * 256 + threadIdx.x;
  if (i >= n4) return;
  f32x4 v = reinterpret_cast<const f32x4*>(in)[i];
  u32 lo = (u32)f2b(v[0]) | ((u32)f2b(v[1]) << 16);
  u32 hi = (u32)f2b(v[2]) | ((u32)f2b(v[3]) << 16);
  reinterpret_cast<u32*>(out)[2 * i]     = lo;
  reinterpret_cast<u32*>(out)[2 * i + 1] = hi;
}

// per batch z: in f32 (C, HW) -> out bf16 (HW, C)
__global__ __launch_bounds__(256) void nchw_to_nhwc(const float* __restrict__ in,
                                                    u16* __restrict__ out) {
  __shared__ float tile[64][65];
  const int z = blockIdx.z;
  in  += (size_t)z * C_DIM * HW;
  out += (size_t)z * HW * C_DIM;
  const int p0 = blockIdx.x * 64;   // pixel tile
  const int c0 = blockIdx.y * 64;   // channel tile
  const int t = threadIdx.x;
  const int col = t & 63, rb = t >> 6;
#pragma unroll
  for (int i = 0; i < 16; ++i) {
    int row = rb + i * 4;           // channel within tile
    tile[row][col] = in[(size_t)(c0 + row) * HW + p0 + col];
  }
  __syncthreads();
  const int c = t & 63, pb = t >> 6;
#pragma unroll
  for (int i = 0; i < 16; ++i) {
    int p = pb + i * 4;             // pixel within tile
    out[(size_t)(p0 + p) * C_DIM + c0 + c] = f2b(tile[c][p]);
  }
}

// per batch z: in bf16 (HW, C) -> out f32 (C, HW)   [final output store]
__global__ __launch_bounds__(256) void nhwc_to_nchw_f32(const u16* __restrict__ in,
                                                        float* __restrict__ out) {
  __shared__ float tile[64][65];
  const int z = blockIdx.z;
  in  += (size_t)z * HW * C_DIM;
  out += (size_t)z * C_DIM * HW;
  const int c0 = blockIdx.x * 64;   // channel tile
  const int r0 = blockIdx.y * 64;   // pixel tile
  const int t = threadIdx.x;
  const int colu = t & 31, rbase = t >> 5;
#pragma unroll
  for (int i = 0; i < 8; ++i) {
    int row = rbase + i * 8;        // pixel within tile
    u32 u = *reinterpret_cast<const u32*>(in + (size_t)(r0 + row) * C_DIM + c0 + colu * 2);
    tile[row][colu * 2]     = __uint_as_float(u << 16);
    tile[row][colu * 2 + 1] = __uint_as_float(u & 0xffff0000u);
  }
  __syncthreads();
  const int rr = t & 63, cb = t >> 6;
#pragma unroll
  for (int i = 0; i < 16; ++i) {
    int cc = cb + i * 4;            // channel within tile
    out[(size_t)(c0 + cc) * HW + r0 + rr] = tile[rr][cc];
  }
}

// ---------------------------------------------------------------------------
// GEMM: D[m,n] = epilogue( sum_k A[m,k]*B[n,k] ), async global_load_lds
// staging (m97 2-barrier structure), 128x128 tile, BK=32, 16x16x32 MFMA.
// MODE 0: bn+silu -> Cb bf16 (stride 256)
// MODE 1: fused value+offset: bn-tile<256 -> Cb bf16 +bias; else Cf f32 +bias2
// MODE 2: +bias,bn,silu -> Cb bf16
// ---------------------------------------------------------------------------
template <int MODE>
__global__ __launch_bounds__(256) void gemm_ep(
    const u16* __restrict__ A, const u16* __restrict__ B,
    u16* __restrict__ Cb, float* __restrict__ Cf, int K, int Nreal,
    const float* __restrict__ bias, const float* __restrict__ bias2,
    const float* __restrict__ gamma, const float* __restrict__ beta,
    const float* __restrict__ mean, const float* __restrict__ var) {
  constexpr int BM = 128, BK = 32;
  __shared__ __align__(16) u16 As[BM * BK];
  __shared__ __align__(16) u16 Bs[BM * BK];
  const int tid  = threadIdx.x;
  const int lane = tid & 63;
  const int wave = tid >> 6;
  const int quad = lane >> 4;
  const int l16  = lane & 15;
  const int bm = blockIdx.x * BM;
  const int bn = blockIdx.y * BM;
  const int wm = (wave & 1) * 64;
  const int wn = (wave >> 1) * 64;

  f32x4 acc[4][4] = {};

  for (int ko = 0; ko < K; ko += BK) {
#pragma unroll
    for (int it = 0; it < 2; ++it) {
      int chunk = it * 256 + tid;          // 16B chunk id, 512 per tile
      int r  = chunk >> 2;                 // tile row 0..127
      int kk = (chunk & 3) << 3;           // k offset 0,8,16,24
      const u16* ga = A + (size_t)(bm + r) * K + (ko + kk);
      int br = bn + r; if (br >= Nreal) br = Nreal - 1;   // clamp (N=368 case)
      const u16* gb = B + (size_t)br * K + (ko + kk);
      u16* la = As + (size_t)(it * 256 + wave * 64) * 8;  // wave-uniform base
      u16* lb = Bs + (size_t)(it * 256 + wave * 64) * 8;
      async_cp16(ga, la);
      async_cp16(gb, lb);
    }
    __syncthreads();   // drains vmcnt (async copies) + prior ds_reads
    const bf16x8* Ap = reinterpret_cast<const bf16x8*>(As);
    const bf16x8* Bp = reinterpret_cast<const bf16x8*>(Bs);
    bf16x8 af[4], bfr[4];
#pragma unroll
    for (int mi = 0; mi < 4; ++mi) af[mi] = Ap[(wm + mi * 16 + l16) * 4 + quad];
#pragma unroll
    for (int ni = 0; ni < 4; ++ni) bfr[ni] = Bp[(wn + ni * 16 + l16) * 4 + quad];
#pragma unroll
    for (int mi = 0; mi < 4; ++mi)
#pragma unroll
      for (int ni = 0; ni < 4; ++ni)
        acc[mi][ni] = __builtin_amdgcn_mfma_f32_16x16x32_bf16(
            af[mi], bfr[ni], acc[mi][ni], 0, 0, 0);
    __syncthreads();
  }

#pragma unroll
  for (int ni = 0; ni < 4; ++ni) {
    int n = bn + wn + ni * 16 + l16;
    if constexpr (MODE == 0 || MODE == 2) {
      float sc = gamma[n] * rsqrtf(var[n] + EPSV);
      float sh = beta[n] - mean[n] * sc;
      if constexpr (MODE == 2) sh += bias[n] * sc;
#pragma unroll
      for (int mi = 0; mi < 4; ++mi) {
        int mrow = bm + wm + mi * 16 + quad * 4;
#pragma unroll
        for (int i = 0; i < 4; ++i) {
          float y = acc[mi][ni][i] * sc + sh;
          y = y / (1.f + __expf(-y));   // silu
          Cb[(size_t)(mrow + i) * C_DIM + n] = f2b(y);
        }
      }
    } else {  // MODE 1: fused value(bf16) + offset(f32)
      if (bn < C_DIM) {
        float sh = bias[n];
#pragma unroll
        for (int mi = 0; mi < 4; ++mi) {
          int mrow = bm + wm + mi * 16 + quad * 4;
#pragma unroll
          for (int i = 0; i < 4; ++i)
            Cb[(size_t)(mrow + i) * C_DIM + n] = f2b(acc[mi][ni][i] + sh);
        }
      } else {
        int col = n - C_DIM;
        bool ok = col < PADOFF;
        float sh = ok ? bias2[col] : 0.f;
#pragma unroll
        for (int mi = 0; mi < 4; ++mi) {
          int mrow = bm + wm + mi * 16 + quad * 4;
#pragma unroll
          for (int i = 0; i < 4; ++i)
            if (ok) Cf[(size_t)(mrow + i) * PADOFF + col] = acc[mi][ni][i] + sh;
        }
      }
    }
  }
}

// ---------------------------------------------------------------------------
// Deformable sampling, v4:
//  - XCD-aware block swizzle: 8 contiguous 512-block chunks -> each XCD sweeps
//    ~64 rows of one image; v gather footprint fits its 4 MiB L2 (was: every
//    XCD touching all 32 MiB of v -> L3-latency-bound at VALUBusy 58%).
//  - packed f32 math: acc as f32x2, __builtin_elementwise_fma -> v_pk_fma_f32
//    halves FMA instruction count (576 -> 288 per thread).
//  - per-tap axis precompute: clamp/bounds per row&col (2x each) instead of
//    per corner (4x); corner address = rowoff+coloff as u32 byte offsets off a
//    single 64-bit base (kills per-corner size_t mul).
// v: (M, C) NHWC bf16 ; om: (M, 112) f32 [per g: 18 offsets(x,y), 9 masks]
// ---------------------------------------------------------------------------
__global__ __launch_bounds__(256) void dcn_sample(
    const u16* __restrict__ v, const float* __restrict__ om,
    u16* __restrict__ outp) {
  __shared__ float sm[16 * PADOFF];   // 1792 f32 = 7 KiB
  const int tid = threadIdx.x;
  // XCD swizzle (gridDim.x = 4096, divisible by 8 -> bijective)
  const int bid = blockIdx.x;
  const int cpx = gridDim.x >> 3;               // blocks per XCD chunk
  const int wg  = (bid & 7) * cpx + (bid >> 3);
  const int m0  = wg * 16;
  {
    const float* src = om + (size_t)m0 * PADOFF;
#pragma unroll
    for (int i = 0; i < 7; ++i) sm[tid + i * 256] = src[tid + i * 256];
  }
  __syncthreads();
  const int c4 = tid & 3;            // 16-channel slice within group
  const int g  = (tid >> 2) & 3;
  const int pl = tid >> 4;           // pixel within block
  const int m  = m0 + pl;
  const int n  = m >> 14;            // HW = 2^14
  const int hw = m & (HW - 1);
  const int h = hw >> 7, w = hw & 127;
  const float* p = sm + pl * PADOFF + g * 27;
  const char* vb = (const char*)(v + (size_t)n * HW * C_DIM + g * CG + c4 * 16);
  f32x2 acc[8] = {};                 // channel pairs (2j, 2j+1)
#pragma unroll
  for (int k = 0; k < 9; ++k) {
    const int di = k / 3 - 1, dj = k % 3 - 1;
    float ox = p[2 * k], oy = p[2 * k + 1], mk = p[18 + k];
    float lh = (float)(h + di) + oy;
    float lw = (float)(w + dj) + ox;
    float fh = floorf(lh), fw = floorf(lw);
    float dh = lh - fh, dw = lw - fw;
    int h0 = (int)fh, w0 = (int)fw;
    // per-axis precompute: clamped byte-offsets + validity
    u32 roff[2], coff[2];
    bool vh[2], vw[2];
#pragma unroll
    for (int t2 = 0; t2 < 2; ++t2) {
      int hh = h0 + t2, ww = w0 + t2;
      vh[t2] = (u32)hh < (u32)H_DIM;
      vw[t2] = (u32)ww < (u32)W_DIM;
      int hc = min(max(hh, 0), H_DIM - 1);
      int wc = min(max(ww, 0), W_DIM - 1);
      roff[t2] = (u32)hc << 16;      // hc * W * C * 2B  = hc << (7+8+1)
      coff[t2] = (u32)wc << 9;       // wc * C * 2B      = wc << (8+1)
    }
    float wy[2] = {(1.f - dh) * mk, dh * mk};
    float wx[2] = {1.f - dw, dw};
#pragma unroll
    for (int cy = 0; cy < 2; ++cy)
#pragma unroll
      for (int cx = 0; cx < 2; ++cx) {
        float wt = (vh[cy] && vw[cx]) ? wy[cy] * wx[cx] : 0.f;
        const char* q = vb + (roff[cy] + coff[cx]);
        u32x4 q0 = *reinterpret_cast<const u32x4*>(q);
        u32x4 q1 = *reinterpret_cast<const u32x4*>(q + 16);
        f32x2 wt2 = {wt, wt};
#pragma unroll
        for (int j = 0; j < 4; ++j) {
          f32x2 v0, v1;
          v0.x = __uint_as_float(q0[j] << 16);
          v0.y = __uint_as_float(q0[j] & 0xffff0000u);
          v1.x = __uint_as_float(q1[j] << 16);
          v1.y = __uint_as_float(q1[j] & 0xffff0000u);
          acc[j]     = __builtin_elementwise_fma(v0, wt2, acc[j]);
          acc[4 + j] = __builtin_elementwise_fma(v1, wt2, acc[4 + j]);
        }
      }
  }
  u32x4 r0, r1;
#pragma unroll
  for (int j = 0; j < 4; ++j) {
    r0[j] = (u32)f2b(acc[j].x)     | ((u32)f2b(acc[j].y) << 16);
    r1[j] = (u32)f2b(acc[4 + j].x) | ((u32)f2b(acc[4 + j].y) << 16);
  }
  u16* o = outp + (size_t)m * C_DIM + g * CG + c4 * 16;
  *reinterpret_cast<u32x4*>(o)     = r0;
  *reinterpret_cast<u32x4*>(o + 8) = r1;
}

// ---------------------------------------------------------------------------
extern "C" void kernel_launch(void* const* d_in, const int* in_sizes, int n_in,
                              void* d_out, int out_size, void* d_ws, size_t ws_size,
                              hipStream_t stream) {
  const float* x        = (const float*)d_in[0];
  const float* conv_w   = (const float*)d_in[1];
  const float* bn1_g    = (const float*)d_in[2];
  const float* bn1_b    = (const float*)d_in[3];
  const float* bn1_m    = (const float*)d_in[4];
  const float* bn1_v    = (const float*)d_in[5];
  const float* value_w  = (const float*)d_in[6];
  const float* value_b  = (const float*)d_in[7];
  const float* offset_w = (const float*)d_in[8];
  const float* offset_b = (const float*)d_in[9];
  const float* out_w    = (const float*)d_in[10];
  const float* out_b    = (const float*)d_in[11];
  const float* bn2_g    = (const float*)d_in[12];
  const float* bn2_b    = (const float*)d_in[13];
  const float* bn2_m    = (const float*)d_in[14];
  const float* bn2_v    = (const float*)d_in[15];

  char* ws = (char*)d_ws;
  u16*   xt   = (u16*)(ws);                    // 32 MiB  (x NHWC bf16)
  u16*   t    = (u16*)(ws + 33554432);         // 32 MiB  (post conv+bn1+silu)
  u16*   vv   = (u16*)(ws + 67108864);         // 32 MiB  (value proj)
  float* om   = (float*)(ws + 100663296);      // 28 MiB  (offset+mask f32)
  u16*   wc   = (u16*)(ws + 130023424);        // conv_w bf16 (128 KiB)
  u16*   wcat = (u16*)(ws + 130154496);        // [value_w; offset_w] bf16 (368x256)
  u16*   wout = (u16*)(ws + 130342912);        // out_w bf16 (128 KiB)
  u16*   dcn  = xt;                            // reuse (xt dead after K1)
  u16*   otmp = t;                             // reuse (t dead after K2)
  float* outp = (float*)d_out;                 // final output is f32

  // W: weights f32 -> bf16 (value+offset concatenated along N)
  cast_w<<<64, 256, 0, stream>>>(conv_w,   wc,           65536 / 4);
  cast_w<<<64, 256, 0, stream>>>(value_w,  wcat,         65536 / 4);
  cast_w<<<28, 256, 0, stream>>>(offset_w, wcat + 65536, (PADOFF * C_DIM) / 4);
  cast_w<<<64, 256, 0, stream>>>(out_w,    wout,         65536 / 4);

  // K0: x f32 NCHW -> bf16 NHWC
  nchw_to_nhwc<<<dim3(HW / 64, C_DIM / 64, N_IMG), 256, 0, stream>>>(x, xt);
  // K1: t = silu(bn1(xt @ conv_w^T))
  gemm_ep<0><<<dim3(M_TOT / 128, 2), 256, 0, stream>>>(
      xt, wc, t, nullptr, C_DIM, C_DIM,
      nullptr, nullptr, bn1_g, bn1_b, bn1_m, bn1_v);
  // K2: fused [vv | om] = t @ [value_w; offset_w]^T + [value_b; offset_b]
  gemm_ep<1><<<dim3(M_TOT / 128, 3), 256, 0, stream>>>(
      t, wcat, vv, om, C_DIM, C_DIM + PADOFF,
      value_b, offset_b, nullptr, nullptr, nullptr, nullptr);
  // K4: deformable bilinear sampling (16 px / block)
  dcn_sample<<<dim3(M_TOT / 16), 256, 0, stream>>>(vv, om, dcn);
  // K5: otmp = silu(bn2(dcn @ out_w^T + out_b))   (bf16 NHWC)
  gemm_ep<2><<<dim3(M_TOT / 128, 2), 256, 0, stream>>>(
      dcn, wout, otmp, nullptr, C_DIM, C_DIM,
      out_b, nullptr, bn2_g, bn2_b, bn2_m, bn2_v);
  // K6: bf16 NHWC -> f32 NCHW (d_out)
  nhwc_to_nchw_f32<<<dim3(C_DIM / 64, HW / 64, N_IMG), 256, 0, stream>>>(otmp, outp);
}

// Round 3
// 314.562 us; speedup vs baseline: 1.1500x; 1.1500x over previous
//
#include <hip/hip_runtime.h>
#include <cstdint>

typedef unsigned short u16;   // bf16 bit pattern
typedef unsigned int   u32;
typedef __attribute__((ext_vector_type(8))) __bf16 bf16x8;
typedef __attribute__((ext_vector_type(4))) float  f32x4;
typedef __attribute__((ext_vector_type(4))) u32    u32x4;

#define N_IMG 4
#define C_DIM 256
#define H_DIM 128
#define W_DIM 128
#define HW    (H_DIM * W_DIM)      // 16384
#define M_TOT (N_IMG * HW)         // 65536
#define CG    64
#define PADOFF 112
#define EPSV  1e-5f

__device__ __forceinline__ u16 f2b(float f) {
  u32 u = __float_as_uint(f);
  u += 0x7fffu + ((u >> 16) & 1u);   // round-to-nearest-even
  return (u16)(u >> 16);
}

// async global->LDS, 16B per lane; LDS dest = wave-uniform base + lane*16
__device__ __forceinline__ void async_cp16(const void* g, void* l) {
  __builtin_amdgcn_global_load_lds(
      (const __attribute__((address_space(1))) void*)g,
      (__attribute__((address_space(3))) void*)l, 16, 0, 0);
}

// cast n f32 -> n bf16, 4 elems/thread
__global__ __launch_bounds__(256) void cast_w(const float* __restrict__ in,
                                              u16* __restrict__ out, int n4) {
  int i = blockIdx.x * 256 + threadIdx.x;
  if (i >= n4) return;
  f32x4 v = reinterpret_cast<const f32x4*>(in)[i];
  u32 lo = (u32)f2b(v[0]) | ((u32)f2b(v[1]) << 16);
  u32 hi = (u32)f2b(v[2]) | ((u32)f2b(v[3]) << 16);
  reinterpret_cast<u32*>(out)[2 * i]     = lo;
  reinterpret_cast<u32*>(out)[2 * i + 1] = hi;
}

// per batch z: in f32 (C, HW) -> out bf16 (HW, C)
__global__ __launch_bounds__(256) void nchw_to_nhwc(const float* __restrict__ in,
                                                    u16* __restrict__ out) {
  __shared__ float tile[64][65];
  const int z = blockIdx.z;
  in  += (size_t)z * C_DIM * HW;
  out += (size_t)z * HW * C_DIM;
  const int p0 = blockIdx.x * 64;   // pixel tile
  const int c0 = blockIdx.y * 64;   // channel tile
  const int t = threadIdx.x;
  const int col = t & 63, rb = t >> 6;
#pragma unroll
  for (int i = 0; i < 16; ++i) {
    int row = rb + i * 4;           // channel within tile
    tile[row][col] = in[(size_t)(c0 + row) * HW + p0 + col];
  }
  __syncthreads();
  const int c = t & 63, pb = t >> 6;
#pragma unroll
  for (int i = 0; i < 16; ++i) {
    int p = pb + i * 4;             // pixel within tile
    out[(size_t)(p0 + p) * C_DIM + c0 + c] = f2b(tile[c][p]);
  }
}

// per batch z: in bf16 (HW, C) -> out f32 (C, HW)   [final output store]
__global__ __launch_bounds__(256) void nhwc_to_nchw_f32(const u16* __restrict__ in,
                                                        float* __restrict__ out) {
  __shared__ float tile[64][65];
  const int z = blockIdx.z;
  in  += (size_t)z * HW * C_DIM;
  out += (size_t)z * C_DIM * HW;
  const int c0 = blockIdx.x * 64;   // channel tile
  const int r0 = blockIdx.y * 64;   // pixel tile
  const int t = threadIdx.x;
  const int colu = t & 31, rbase = t >> 5;
#pragma unroll
  for (int i = 0; i < 8; ++i) {
    int row = rbase + i * 8;        // pixel within tile
    u32 u = *reinterpret_cast<const u32*>(in + (size_t)(r0 + row) * C_DIM + c0 + colu * 2);
    tile[row][colu * 2]     = __uint_as_float(u << 16);
    tile[row][colu * 2 + 1] = __uint_as_float(u & 0xffff0000u);
  }
  __syncthreads();
  const int rr = t & 63, cb = t >> 6;
#pragma unroll
  for (int i = 0; i < 16; ++i) {
    int cc = cb + i * 4;            // channel within tile
    out[(size_t)(c0 + cc) * HW + r0 + rr] = tile[rr][cc];
  }
}

// ---------------------------------------------------------------------------
// GEMM: D[m,n] = epilogue( sum_k A[m,k]*B[n,k] ), async global_load_lds
// staging (m97 2-barrier structure), 128x128 tile, BK=32, 16x16x32 MFMA.
// MODE 0: bn+silu -> Cb bf16 (stride 256)
// MODE 1: fused value+offset: bn-tile<256 -> Cb bf16 +bias; else Cf f32 +bias2
// MODE 2: +bias,bn,silu -> Cb bf16
// ---------------------------------------------------------------------------
template <int MODE>
__global__ __launch_bounds__(256) void gemm_ep(
    const u16* __restrict__ A, const u16* __restrict__ B,
    u16* __restrict__ Cb, float* __restrict__ Cf, int K, int Nreal,
    const float* __restrict__ bias, const float* __restrict__ bias2,
    const float* __restrict__ gamma, const float* __restrict__ beta,
    const float* __restrict__ mean, const float* __restrict__ var) {
  constexpr int BM = 128, BK = 32;
  __shared__ __align__(16) u16 As[BM * BK];
  __shared__ __align__(16) u16 Bs[BM * BK];
  const int tid  = threadIdx.x;
  const int lane = tid & 63;
  const int wave = tid >> 6;
  const int quad = lane >> 4;
  const int l16  = lane & 15;
  const int bm = blockIdx.x * BM;
  const int bn = blockIdx.y * BM;
  const int wm = (wave & 1) * 64;
  const int wn = (wave >> 1) * 64;

  f32x4 acc[4][4] = {};

  for (int ko = 0; ko < K; ko += BK) {
#pragma unroll
    for (int it = 0; it < 2; ++it) {
      int chunk = it * 256 + tid;          // 16B chunk id, 512 per tile
      int r  = chunk >> 2;                 // tile row 0..127
      int kk = (chunk & 3) << 3;           // k offset 0,8,16,24
      const u16* ga = A + (size_t)(bm + r) * K + (ko + kk);
      int br = bn + r; if (br >= Nreal) br = Nreal - 1;   // clamp (N=368 case)
      const u16* gb = B + (size_t)br * K + (ko + kk);
      u16* la = As + (size_t)(it * 256 + wave * 64) * 8;  // wave-uniform base
      u16* lb = Bs + (size_t)(it * 256 + wave * 64) * 8;
      async_cp16(ga, la);
      async_cp16(gb, lb);
    }
    __syncthreads();   // drains vmcnt (async copies) + prior ds_reads
    const bf16x8* Ap = reinterpret_cast<const bf16x8*>(As);
    const bf16x8* Bp = reinterpret_cast<const bf16x8*>(Bs);
    bf16x8 af[4], bfr[4];
#pragma unroll
    for (int mi = 0; mi < 4; ++mi) af[mi] = Ap[(wm + mi * 16 + l16) * 4 + quad];
#pragma unroll
    for (int ni = 0; ni < 4; ++ni) bfr[ni] = Bp[(wn + ni * 16 + l16) * 4 + quad];
#pragma unroll
    for (int mi = 0; mi < 4; ++mi)
#pragma unroll
      for (int ni = 0; ni < 4; ++ni)
        acc[mi][ni] = __builtin_amdgcn_mfma_f32_16x16x32_bf16(
            af[mi], bfr[ni], acc[mi][ni], 0, 0, 0);
    __syncthreads();
  }

#pragma unroll
  for (int ni = 0; ni < 4; ++ni) {
    int n = bn + wn + ni * 16 + l16;
    if constexpr (MODE == 0 || MODE == 2) {
      float sc = gamma[n] * rsqrtf(var[n] + EPSV);
      float sh = beta[n] - mean[n] * sc;
      if constexpr (MODE == 2) sh += bias[n] * sc;
#pragma unroll
      for (int mi = 0; mi < 4; ++mi) {
        int mrow = bm + wm + mi * 16 + quad * 4;
#pragma unroll
        for (int i = 0; i < 4; ++i) {
          float y = acc[mi][ni][i] * sc + sh;
          y = y / (1.f + __expf(-y));   // silu
          Cb[(size_t)(mrow + i) * C_DIM + n] = f2b(y);
        }
      }
    } else {  // MODE 1: fused value(bf16) + offset(f32)
      if (bn < C_DIM) {
        float sh = bias[n];
#pragma unroll
        for (int mi = 0; mi < 4; ++mi) {
          int mrow = bm + wm + mi * 16 + quad * 4;
#pragma unroll
          for (int i = 0; i < 4; ++i)
            Cb[(size_t)(mrow + i) * C_DIM + n] = f2b(acc[mi][ni][i] + sh);
        }
      } else {
        int col = n - C_DIM;
        bool ok = col < PADOFF;
        float sh = ok ? bias2[col] : 0.f;
#pragma unroll
        for (int mi = 0; mi < 4; ++mi) {
          int mrow = bm + wm + mi * 16 + quad * 4;
#pragma unroll
          for (int i = 0; i < 4; ++i)
            if (ok) Cf[(size_t)(mrow + i) * PADOFF + col] = acc[mi][ni][i] + sh;
        }
      }
    }
  }
}

// ---------------------------------------------------------------------------
// Deformable sampling, v5 = v3 body (88 VGPR, 5 waves/SIMD) + XCD swizzle.
// v4 post-mortem: packed-f32 + per-axis precompute ballooned VGPR 88->232,
// occupancy 5->2 waves/SIMD, dur 63->112us. Latency-bound kernel: occupancy
// beats instruction count. Swizzle alone cut FETCH_SIZE 34.4->31.3 MB (keep).
// Round-2 bench aborted in the pytest process before the bench loop (no HIP
// error, no rocprof) — infra flake; resubmitting unchanged for the A/B.
// v: (M, C) NHWC bf16 ; om: (M, 112) f32 [per g: 18 offsets(x,y), 9 masks]
// ---------------------------------------------------------------------------
__global__ __launch_bounds__(256) void dcn_sample(
    const u16* __restrict__ v, const float* __restrict__ om,
    u16* __restrict__ outp) {
  __shared__ float sm[16 * PADOFF];   // 1792 f32 = 7 KiB
  const int tid = threadIdx.x;
  // XCD swizzle (gridDim.x = 4096, divisible by 8 -> bijective):
  // each XCD sweeps a contiguous 512-block chunk (~64 rows of one image) so
  // the v gather footprint (~4.3 MB) mostly fits its private 4 MiB L2.
  const int bid = blockIdx.x;
  const int cpx = gridDim.x >> 3;               // blocks per XCD chunk
  const int wg  = (bid & 7) * cpx + (bid >> 3);
  const int m0  = wg * 16;
  {
    const float* src = om + (size_t)m0 * PADOFF;
#pragma unroll
    for (int i = 0; i < 7; ++i) sm[tid + i * 256] = src[tid + i * 256];
  }
  __syncthreads();
  const int c4 = tid & 3;            // 16-channel slice within group
  const int g  = (tid >> 2) & 3;
  const int pl = tid >> 4;           // pixel within block
  const int m  = m0 + pl;
  const int n  = m >> 14;            // HW = 2^14
  const int hw = m & (HW - 1);
  const int h = hw >> 7, w = hw & 127;
  const float* p = sm + pl * PADOFF + g * 27;
  const u16* vb = v + (size_t)n * HW * C_DIM + g * CG + c4 * 16;
  float acc[16] = {};
#pragma unroll
  for (int k = 0; k < 9; ++k) {
    const int di = k / 3 - 1, dj = k % 3 - 1;
    float ox = p[2 * k], oy = p[2 * k + 1], mk = p[18 + k];
    float lh = (float)(h + di) + oy;
    float lw = (float)(w + dj) + ox;
    float fh = floorf(lh), fw = floorf(lw);
    float dh = lh - fh, dw = lw - fw;
    int h0 = (int)fh, w0 = (int)fw;
    float wy[2] = {(1.f - dh) * mk, dh * mk};
    float wx[2] = {1.f - dw, dw};
#pragma unroll
    for (int cy = 0; cy < 2; ++cy)
#pragma unroll
      for (int cx = 0; cx < 2; ++cx) {
        int hh = h0 + cy, ww = w0 + cx;
        bool ok = ((u32)hh < (u32)H_DIM) & ((u32)ww < (u32)W_DIM);
        float wt = ok ? wy[cy] * wx[cx] : 0.f;
        int hc = min(max(hh, 0), H_DIM - 1);
        int wc = min(max(ww, 0), W_DIM - 1);
        const u16* q = vb + (size_t)((hc << 7) + wc) * C_DIM;
        u32x4 q0 = *reinterpret_cast<const u32x4*>(q);
        u32x4 q1 = *reinterpret_cast<const u32x4*>(q + 8);
#pragma unroll
        for (int j = 0; j < 4; ++j) {
          acc[2 * j]     += wt * __uint_as_float(q0[j] << 16);
          acc[2 * j + 1] += wt * __uint_as_float(q0[j] & 0xffff0000u);
          acc[8 + 2 * j]     += wt * __uint_as_float(q1[j] << 16);
          acc[8 + 2 * j + 1] += wt * __uint_as_float(q1[j] & 0xffff0000u);
        }
      }
  }
  u32x4 r0, r1;
#pragma unroll
  for (int j = 0; j < 4; ++j) {
    r0[j] = (u32)f2b(acc[2 * j])     | ((u32)f2b(acc[2 * j + 1]) << 16);
    r1[j] = (u32)f2b(acc[8 + 2 * j]) | ((u32)f2b(acc[8 + 2 * j + 1]) << 16);
  }
  u16* o = outp + (size_t)m * C_DIM + g * CG + c4 * 16;
  *reinterpret_cast<u32x4*>(o)     = r0;
  *reinterpret_cast<u32x4*>(o + 8) = r1;
}

// ---------------------------------------------------------------------------
extern "C" void kernel_launch(void* const* d_in, const int* in_sizes, int n_in,
                              void* d_out, int out_size, void* d_ws, size_t ws_size,
                              hipStream_t stream) {
  const float* x        = (const float*)d_in[0];
  const float* conv_w   = (const float*)d_in[1];
  const float* bn1_g    = (const float*)d_in[2];
  const float* bn1_b    = (const float*)d_in[3];
  const float* bn1_m    = (const float*)d_in[4];
  const float* bn1_v    = (const float*)d_in[5];
  const float* value_w  = (const float*)d_in[6];
  const float* value_b  = (const float*)d_in[7];
  const float* offset_w = (const float*)d_in[8];
  const float* offset_b = (const float*)d_in[9];
  const float* out_w    = (const float*)d_in[10];
  const float* out_b    = (const float*)d_in[11];
  const float* bn2_g    = (const float*)d_in[12];
  const float* bn2_b    = (const float*)d_in[13];
  const float* bn2_m    = (const float*)d_in[14];
  const float* bn2_v    = (const float*)d_in[15];

  char* ws = (char*)d_ws;
  u16*   xt   = (u16*)(ws);                    // 32 MiB  (x NHWC bf16)
  u16*   t    = (u16*)(ws + 33554432);         // 32 MiB  (post conv+bn1+silu)
  u16*   vv   = (u16*)(ws + 67108864);         // 32 MiB  (value proj)
  float* om   = (float*)(ws + 100663296);      // 28 MiB  (offset+mask f32)
  u16*   wc   = (u16*)(ws + 130023424);        // conv_w bf16 (128 KiB)
  u16*   wcat = (u16*)(ws + 130154496);        // [value_w; offset_w] bf16 (368x256)
  u16*   wout = (u16*)(ws + 130342912);        // out_w bf16 (128 KiB)
  u16*   dcn  = xt;                            // reuse (xt dead after K1)
  u16*   otmp = t;                             // reuse (t dead after K2)
  float* outp = (float*)d_out;                 // final output is f32

  // W: weights f32 -> bf16 (value+offset concatenated along N)
  cast_w<<<64, 256, 0, stream>>>(conv_w,   wc,           65536 / 4);
  cast_w<<<64, 256, 0, stream>>>(value_w,  wcat,         65536 / 4);
  cast_w<<<28, 256, 0, stream>>>(offset_w, wcat + 65536, (PADOFF * C_DIM) / 4);
  cast_w<<<64, 256, 0, stream>>>(out_w,    wout,         65536 / 4);

  // K0: x f32 NCHW -> bf16 NHWC
  nchw_to_nhwc<<<dim3(HW / 64, C_DIM / 64, N_IMG), 256, 0, stream>>>(x, xt);
  // K1: t = silu(bn1(xt @ conv_w^T))
  gemm_ep<0><<<dim3(M_TOT / 128, 2), 256, 0, stream>>>(
      xt, wc, t, nullptr, C_DIM, C_DIM,
      nullptr, nullptr, bn1_g, bn1_b, bn1_m, bn1_v);
  // K2: fused [vv | om] = t @ [value_w; offset_w]^T + [value_b; offset_b]
  gemm_ep<1><<<dim3(M_TOT / 128, 3), 256, 0, stream>>>(
      t, wcat, vv, om, C_DIM, C_DIM + PADOFF,
      value_b, offset_b, nullptr, nullptr, nullptr, nullptr);
  // K4: deformable bilinear sampling (16 px / block)
  dcn_sample<<<dim3(M_TOT / 16), 256, 0, stream>>>(vv, om, dcn);
  // K5: otmp = silu(bn2(dcn @ out_w^T + out_b))   (bf16 NHWC)
  gemm_ep<2><<<dim3(M_TOT / 128, 2), 256, 0, stream>>>(
      dcn, wout, otmp, nullptr, C_DIM, C_DIM,
      out_b, nullptr, bn2_g, bn2_b, bn2_m, bn2_v);
  // K6: bf16 NHWC -> f32 NCHW (d_out)
  nhwc_to_nchw_f32<<<dim3(C_DIM / 64, HW / 64, N_IMG), 256, 0, stream>>>(otmp, outp);
}

// Round 4
// 298.793 us; speedup vs baseline: 1.2107x; 1.0528x over previous
//
#include <hip/hip_runtime.h>
#include <cstdint>

typedef unsigned short u16;   // bf16 bit pattern
typedef unsigned int   u32;
typedef __attribute__((ext_vector_type(8))) __bf16 bf16x8;
typedef __attribute__((ext_vector_type(4))) float  f32x4;
typedef __attribute__((ext_vector_type(4))) u32    u32x4;

#define N_IMG 4
#define C_DIM 256
#define H_DIM 128
#define W_DIM 128
#define HW    (H_DIM * W_DIM)      // 16384
#define M_TOT (N_IMG * HW)         // 65536
#define CG    64
#define PADOFF 112
#define EPSV  1e-5f

__device__ __forceinline__ u16 f2b(float f) {
  u32 u = __float_as_uint(f);
  u += 0x7fffu + ((u >> 16) & 1u);   // round-to-nearest-even
  return (u16)(u >> 16);
}

// async global->LDS, 16B per lane; LDS dest = wave-uniform base + lane*16
__device__ __forceinline__ void async_cp16(const void* g, void* l) {
  __builtin_amdgcn_global_load_lds(
      (const __attribute__((address_space(1))) void*)g,
      (__attribute__((address_space(3))) void*)l, 16, 0, 0);
}

// all four weight tensors f32 -> bf16 in ONE launch (was 4 cast_w dispatches).
// f32x4 segment sizes: conv 16384 | value 16384 | offset 7168 | out 16384
// total 56320 = 220 blocks * 256 threads exactly.
__global__ __launch_bounds__(256) void cast_all(
    const float* __restrict__ a0, u16* __restrict__ o0,
    const float* __restrict__ a1, u16* __restrict__ o1,
    const float* __restrict__ a2, u16* __restrict__ o2,
    const float* __restrict__ a3, u16* __restrict__ o3) {
  int i = blockIdx.x * 256 + threadIdx.x;
  const float* in; u16* out; int base;
  if (i < 16384)      { in = a0; out = o0; base = 0; }
  else if (i < 32768) { in = a1; out = o1; base = 16384; }
  else if (i < 39936) { in = a2; out = o2; base = 32768; }
  else                { in = a3; out = o3; base = 39936; }
  int j = i - base;
  f32x4 v = reinterpret_cast<const f32x4*>(in)[j];
  u32 lo = (u32)f2b(v[0]) | ((u32)f2b(v[1]) << 16);
  u32 hi = (u32)f2b(v[2]) | ((u32)f2b(v[3]) << 16);
  reinterpret_cast<u32*>(out)[2 * j]     = lo;
  reinterpret_cast<u32*>(out)[2 * j + 1] = hi;
}

// per batch z: in f32 (C, HW) -> out bf16 (HW, C)
__global__ __launch_bounds__(256) void nchw_to_nhwc(const float* __restrict__ in,
                                                    u16* __restrict__ out) {
  __shared__ float tile[64][65];
  const int z = blockIdx.z;
  in  += (size_t)z * C_DIM * HW;
  out += (size_t)z * HW * C_DIM;
  const int p0 = blockIdx.x * 64;   // pixel tile
  const int c0 = blockIdx.y * 64;   // channel tile
  const int t = threadIdx.x;
  const int col = t & 63, rb = t >> 6;
#pragma unroll
  for (int i = 0; i < 16; ++i) {
    int row = rb + i * 4;           // channel within tile
    tile[row][col] = in[(size_t)(c0 + row) * HW + p0 + col];
  }
  __syncthreads();
  const int c = t & 63, pb = t >> 6;
#pragma unroll
  for (int i = 0; i < 16; ++i) {
    int p = pb + i * 4;             // pixel within tile
    out[(size_t)(p0 + p) * C_DIM + c0 + c] = f2b(tile[c][p]);
  }
}

// per batch z: in bf16 (HW, C) -> out f32 (C, HW)   [final output store]
__global__ __launch_bounds__(256) void nhwc_to_nchw_f32(const u16* __restrict__ in,
                                                        float* __restrict__ out) {
  __shared__ float tile[64][65];
  const int z = blockIdx.z;
  in  += (size_t)z * HW * C_DIM;
  out += (size_t)z * C_DIM * HW;
  const int c0 = blockIdx.x * 64;   // channel tile
  const int r0 = blockIdx.y * 64;   // pixel tile
  const int t = threadIdx.x;
  const int colu = t & 31, rbase = t >> 5;
#pragma unroll
  for (int i = 0; i < 8; ++i) {
    int row = rbase + i * 8;        // pixel within tile
    u32 u = *reinterpret_cast<const u32*>(in + (size_t)(r0 + row) * C_DIM + c0 + colu * 2);
    tile[row][colu * 2]     = __uint_as_float(u << 16);
    tile[row][colu * 2 + 1] = __uint_as_float(u & 0xffff0000u);
  }
  __syncthreads();
  const int rr = t & 63, cb = t >> 6;
#pragma unroll
  for (int i = 0; i < 16; ++i) {
    int cc = cb + i * 4;            // channel within tile
    out[(size_t)(c0 + cc) * HW + r0 + rr] = tile[rr][cc];
  }
}

// ---------------------------------------------------------------------------
// GEMM: D[m,n] = epilogue( sum_k A[m,k]*B[n,k] ), async global_load_lds
// staging (m97 2-barrier structure), 128x128 tile, BK=32, 16x16x32 MFMA.
// MODE 0: bn+silu -> Cb bf16 (stride 256)
// MODE 1: fused value+offset: bn-tile<256 -> Cb bf16 +bias; else Cf f32 +bias2
// MODE 2: +bias,bn,silu -> Cb bf16
// ---------------------------------------------------------------------------
template <int MODE>
__global__ __launch_bounds__(256) void gemm_ep(
    const u16* __restrict__ A, const u16* __restrict__ B,
    u16* __restrict__ Cb, float* __restrict__ Cf, int K, int Nreal,
    const float* __restrict__ bias, const float* __restrict__ bias2,
    const float* __restrict__ gamma, const float* __restrict__ beta,
    const float* __restrict__ mean, const float* __restrict__ var) {
  constexpr int BM = 128, BK = 32;
  __shared__ __align__(16) u16 As[BM * BK];
  __shared__ __align__(16) u16 Bs[BM * BK];
  const int tid  = threadIdx.x;
  const int lane = tid & 63;
  const int wave = tid >> 6;
  const int quad = lane >> 4;
  const int l16  = lane & 15;
  const int bm = blockIdx.x * BM;
  const int bn = blockIdx.y * BM;
  const int wm = (wave & 1) * 64;
  const int wn = (wave >> 1) * 64;

  f32x4 acc[4][4] = {};

  for (int ko = 0; ko < K; ko += BK) {
#pragma unroll
    for (int it = 0; it < 2; ++it) {
      int chunk = it * 256 + tid;          // 16B chunk id, 512 per tile
      int r  = chunk >> 2;                 // tile row 0..127
      int kk = (chunk & 3) << 3;           // k offset 0,8,16,24
      const u16* ga = A + (size_t)(bm + r) * K + (ko + kk);
      int br = bn + r; if (br >= Nreal) br = Nreal - 1;   // clamp (N=368 case)
      const u16* gb = B + (size_t)br * K + (ko + kk);
      u16* la = As + (size_t)(it * 256 + wave * 64) * 8;  // wave-uniform base
      u16* lb = Bs + (size_t)(it * 256 + wave * 64) * 8;
      async_cp16(ga, la);
      async_cp16(gb, lb);
    }
    __syncthreads();   // drains vmcnt (async copies) + prior ds_reads
    const bf16x8* Ap = reinterpret_cast<const bf16x8*>(As);
    const bf16x8* Bp = reinterpret_cast<const bf16x8*>(Bs);
    bf16x8 af[4], bfr[4];
#pragma unroll
    for (int mi = 0; mi < 4; ++mi) af[mi] = Ap[(wm + mi * 16 + l16) * 4 + quad];
#pragma unroll
    for (int ni = 0; ni < 4; ++ni) bfr[ni] = Bp[(wn + ni * 16 + l16) * 4 + quad];
#pragma unroll
    for (int mi = 0; mi < 4; ++mi)
#pragma unroll
      for (int ni = 0; ni < 4; ++ni)
        acc[mi][ni] = __builtin_amdgcn_mfma_f32_16x16x32_bf16(
            af[mi], bfr[ni], acc[mi][ni], 0, 0, 0);
    __syncthreads();
  }

#pragma unroll
  for (int ni = 0; ni < 4; ++ni) {
    int n = bn + wn + ni * 16 + l16;
    if constexpr (MODE == 0 || MODE == 2) {
      float sc = gamma[n] * rsqrtf(var[n] + EPSV);
      float sh = beta[n] - mean[n] * sc;
      if constexpr (MODE == 2) sh += bias[n] * sc;
#pragma unroll
      for (int mi = 0; mi < 4; ++mi) {
        int mrow = bm + wm + mi * 16 + quad * 4;
#pragma unroll
        for (int i = 0; i < 4; ++i) {
          float y = acc[mi][ni][i] * sc + sh;
          y = y / (1.f + __expf(-y));   // silu
          Cb[(size_t)(mrow + i) * C_DIM + n] = f2b(y);
        }
      }
    } else {  // MODE 1: fused value(bf16) + offset(f32)
      if (bn < C_DIM) {
        float sh = bias[n];
#pragma unroll
        for (int mi = 0; mi < 4; ++mi) {
          int mrow = bm + wm + mi * 16 + quad * 4;
#pragma unroll
          for (int i = 0; i < 4; ++i)
            Cb[(size_t)(mrow + i) * C_DIM + n] = f2b(acc[mi][ni][i] + sh);
        }
      } else {
        int col = n - C_DIM;
        bool ok = col < PADOFF;
        float sh = ok ? bias2[col] : 0.f;
#pragma unroll
        for (int mi = 0; mi < 4; ++mi) {
          int mrow = bm + wm + mi * 16 + quad * 4;
#pragma unroll
          for (int i = 0; i < 4; ++i)
            if (ok) Cf[(size_t)(mrow + i) * PADOFF + col] = acc[mi][ni][i] + sh;
        }
      }
    }
  }
}

// ---------------------------------------------------------------------------
// Deformable sampling, v6 = v5 structure (16 ch/thread, 16 px/block, XCD
// swizzle) with a dot2-packed inner loop:
//  - per tap row (cy), the two horizontal corners (cx=0,1) are PAIRED:
//    v_perm_b32 packs (cornerA.ch, cornerB.ch) bf16 halves into one dword,
//    v_dot2_f32_bf16 does ch*wtA + ch*wtB + acc in ONE instr.
//    Core stream per corner-pair per 16ch: 32 ops (16 unpack+16 fma) -> 16
//    (8 perm + 8 dot2). ~-40% VALU instrs/thread overall.
//  - weights packed to bf16 via v_cvt_pk_bf16_f32 (1 op; weight quantization
//    ~2^-9 rel, same order as existing bf16 storage error).
//  - output pack via cvt_pk (8 ops replace 16 f2b sequences).
// v4 lesson enforced: no per-axis offset arrays, no f32x2 acc — keep live
// state flat so VGPR stays ~<=102 (5 waves/SIMD).
// v: (M, C) NHWC bf16 ; om: (M, 112) f32 [per g: 18 offsets(x,y), 9 masks]
// ---------------------------------------------------------------------------
__global__ __launch_bounds__(256) void dcn_sample(
    const u16* __restrict__ v, const float* __restrict__ om,
    u16* __restrict__ outp) {
  __shared__ float sm[16 * PADOFF];   // 1792 f32 = 7 KiB
  const int tid = threadIdx.x;
  // XCD swizzle (gridDim.x = 4096, divisible by 8 -> bijective)
  const int bid = blockIdx.x;
  const int cpx = gridDim.x >> 3;               // blocks per XCD chunk
  const int wg  = (bid & 7) * cpx + (bid >> 3);
  const int m0  = wg * 16;
  {
    const float* src = om + (size_t)m0 * PADOFF;
#pragma unroll
    for (int i = 0; i < 7; ++i) sm[tid + i * 256] = src[tid + i * 256];
  }
  __syncthreads();
  const int c4 = tid & 3;            // 16-channel slice within group
  const int g  = (tid >> 2) & 3;
  const int pl = tid >> 4;           // pixel within block
  const int m  = m0 + pl;
  const int n  = m >> 14;            // HW = 2^14
  const int hw = m & (HW - 1);
  const int h = hw >> 7, w = hw & 127;
  const float* p = sm + pl * PADOFF + g * 27;
  const u16* vb = v + (size_t)n * HW * C_DIM + g * CG + c4 * 16;
  float acc[16] = {};
#pragma unroll
  for (int k = 0; k < 9; ++k) {
    const int di = k / 3 - 1, dj = k % 3 - 1;
    float ox = p[2 * k], oy = p[2 * k + 1], mk = p[18 + k];
    float lh = (float)(h + di) + oy;
    float lw = (float)(w + dj) + ox;
    float fh = floorf(lh), fw = floorf(lw);
    float dh = lh - fh, dw = lw - fw;
    int h0 = (int)fh, w0 = (int)fw;
    float wy0 = (1.f - dh) * mk, wy1 = dh * mk;
    float wx0 = 1.f - dw, wx1 = dw;
    // horizontal pair: clamped cols + validity (shared across both rows)
    bool okw0 = (u32)w0 < (u32)W_DIM;
    bool okw1 = (u32)(w0 + 1) < (u32)W_DIM;
    int w0c = min(max(w0, 0), W_DIM - 1);
    int w1c = min(max(w0 + 1, 0), W_DIM - 1);
#pragma unroll
    for (int cy = 0; cy < 2; ++cy) {
      int hh = h0 + cy;
      bool okh = (u32)hh < (u32)H_DIM;
      int hc = min(max(hh, 0), H_DIM - 1);
      const u16* rowp = vb + (size_t)(hc << 7) * C_DIM;
      const u16* qA = rowp + (size_t)w0c * C_DIM;
      const u16* qB = rowp + (size_t)w1c * C_DIM;
      u32x4 a0 = *reinterpret_cast<const u32x4*>(qA);
      u32x4 a1 = *reinterpret_cast<const u32x4*>(qA + 8);
      u32x4 b0 = *reinterpret_cast<const u32x4*>(qB);
      u32x4 b1 = *reinterpret_cast<const u32x4*>(qB + 8);
      float wyc = (cy == 0) ? wy0 : wy1;
      float wtA = (okh && okw0) ? wyc * wx0 : 0.f;
      float wtB = (okh && okw1) ? wyc * wx1 : 0.f;
      u32 wp;
      asm("v_cvt_pk_bf16_f32 %0, %1, %2" : "=v"(wp) : "v"(wtA), "v"(wtB));
#pragma unroll
      for (int j = 0; j < 4; ++j) {
        // pack (A.chLo, B.chLo) and (A.chHi, B.chHi) bf16 halves
        u32 lo0 = __builtin_amdgcn_perm(a0[j], b0[j], 0x01000504u);
        u32 hi0 = __builtin_amdgcn_perm(a0[j], b0[j], 0x03020706u);
        u32 lo1 = __builtin_amdgcn_perm(a1[j], b1[j], 0x01000504u);
        u32 hi1 = __builtin_amdgcn_perm(a1[j], b1[j], 0x03020706u);
        asm("v_dot2_f32_bf16 %0, %1, %2, %3"
            : "=v"(acc[2 * j]) : "v"(lo0), "v"(wp), "v"(acc[2 * j]));
        asm("v_dot2_f32_bf16 %0, %1, %2, %3"
            : "=v"(acc[2 * j + 1]) : "v"(hi0), "v"(wp), "v"(acc[2 * j + 1]));
        asm("v_dot2_f32_bf16 %0, %1, %2, %3"
            : "=v"(acc[8 + 2 * j]) : "v"(lo1), "v"(wp), "v"(acc[8 + 2 * j]));
        asm("v_dot2_f32_bf16 %0, %1, %2, %3"
            : "=v"(acc[8 + 2 * j + 1]) : "v"(hi1), "v"(wp), "v"(acc[8 + 2 * j + 1]));
      }
    }
  }
  u32x4 r0, r1;
#pragma unroll
  for (int j = 0; j < 4; ++j) {
    u32 pa, pb;
    asm("v_cvt_pk_bf16_f32 %0, %1, %2"
        : "=v"(pa) : "v"(acc[2 * j]), "v"(acc[2 * j + 1]));
    asm("v_cvt_pk_bf16_f32 %0, %1, %2"
        : "=v"(pb) : "v"(acc[8 + 2 * j]), "v"(acc[8 + 2 * j + 1]));
    r0[j] = pa; r1[j] = pb;
  }
  u16* o = outp + (size_t)m * C_DIM + g * CG + c4 * 16;
  *reinterpret_cast<u32x4*>(o)     = r0;
  *reinterpret_cast<u32x4*>(o + 8) = r1;
}

// ---------------------------------------------------------------------------
extern "C" void kernel_launch(void* const* d_in, const int* in_sizes, int n_in,
                              void* d_out, int out_size, void* d_ws, size_t ws_size,
                              hipStream_t stream) {
  const float* x        = (const float*)d_in[0];
  const float* conv_w   = (const float*)d_in[1];
  const float* bn1_g    = (const float*)d_in[2];
  const float* bn1_b    = (const float*)d_in[3];
  const float* bn1_m    = (const float*)d_in[4];
  const float* bn1_v    = (const float*)d_in[5];
  const float* value_w  = (const float*)d_in[6];
  const float* value_b  = (const float*)d_in[7];
  const float* offset_w = (const float*)d_in[8];
  const float* offset_b = (const float*)d_in[9];
  const float* out_w    = (const float*)d_in[10];
  const float* out_b    = (const float*)d_in[11];
  const float* bn2_g    = (const float*)d_in[12];
  const float* bn2_b    = (const float*)d_in[13];
  const float* bn2_m    = (const float*)d_in[14];
  const float* bn2_v    = (const float*)d_in[15];

  char* ws = (char*)d_ws;
  u16*   xt   = (u16*)(ws);                    // 32 MiB  (x NHWC bf16)
  u16*   t    = (u16*)(ws + 33554432);         // 32 MiB  (post conv+bn1+silu)
  u16*   vv   = (u16*)(ws + 67108864);         // 32 MiB  (value proj)
  float* om   = (float*)(ws + 100663296);      // 28 MiB  (offset+mask f32)
  u16*   wc   = (u16*)(ws + 130023424);        // conv_w bf16 (128 KiB)
  u16*   wcat = (u16*)(ws + 130154496);        // [value_w; offset_w] bf16 (368x256)
  u16*   wout = (u16*)(ws + 130342912);        // out_w bf16 (128 KiB)
  u16*   dcn  = xt;                            // reuse (xt dead after K1)
  u16*   otmp = t;                             // reuse (t dead after K2)
  float* outp = (float*)d_out;                 // final output is f32

  // W: all weights f32 -> bf16 in one launch (value+offset concatenated)
  cast_all<<<220, 256, 0, stream>>>(conv_w, wc, value_w, wcat,
                                    offset_w, wcat + 65536, out_w, wout);

  // K0: x f32 NCHW -> bf16 NHWC
  nchw_to_nhwc<<<dim3(HW / 64, C_DIM / 64, N_IMG), 256, 0, stream>>>(x, xt);
  // K1: t = silu(bn1(xt @ conv_w^T))
  gemm_ep<0><<<dim3(M_TOT / 128, 2), 256, 0, stream>>>(
      xt, wc, t, nullptr, C_DIM, C_DIM,
      nullptr, nullptr, bn1_g, bn1_b, bn1_m, bn1_v);
  // K2: fused [vv | om] = t @ [value_w; offset_w]^T + [value_b; offset_b]
  gemm_ep<1><<<dim3(M_TOT / 128, 3), 256, 0, stream>>>(
      t, wcat, vv, om, C_DIM, C_DIM + PADOFF,
      value_b, offset_b, nullptr, nullptr, nullptr, nullptr);
  // K4: deformable bilinear sampling (16 px / block)
  dcn_sample<<<dim3(M_TOT / 16), 256, 0, stream>>>(vv, om, dcn);
  // K5: otmp = silu(bn2(dcn @ out_w^T + out_b))   (bf16 NHWC)
  gemm_ep<2><<<dim3(M_TOT / 128, 2), 256, 0, stream>>>(
      dcn, wout, otmp, nullptr, C_DIM, C_DIM,
      out_b, nullptr, bn2_g, bn2_b, bn2_m, bn2_v);
  // K6: bf16 NHWC -> f32 NCHW (d_out)
  nhwc_to_nchw_f32<<<dim3(C_DIM / 64, HW / 64, N_IMG), 256, 0, stream>>>(otmp, outp);
}

// Round 5
// 284.642 us; speedup vs baseline: 1.2709x; 1.0497x over previous
//
#include <hip/hip_runtime.h>
#include <cstdint>

typedef unsigned short u16;   // bf16 bit pattern
typedef unsigned int   u32;
typedef __attribute__((ext_vector_type(8))) __bf16 bf16x8;
typedef __attribute__((ext_vector_type(4))) float  f32x4;
typedef __attribute__((ext_vector_type(4))) u32    u32x4;

#define N_IMG 4
#define C_DIM 256
#define H_DIM 128
#define W_DIM 128
#define HW    (H_DIM * W_DIM)      // 16384
#define M_TOT (N_IMG * HW)         // 65536
#define CG    64
#define PADOFF 112
#define EPSV  1e-5f

__device__ __forceinline__ u16 f2b(float f) {
  u32 u = __float_as_uint(f);
  u += 0x7fffu + ((u >> 16) & 1u);   // round-to-nearest-even
  return (u16)(u >> 16);
}

// async global->LDS, 16B per lane; LDS dest = wave-uniform base + lane*16
__device__ __forceinline__ void async_cp16(const void* g, void* l) {
  __builtin_amdgcn_global_load_lds(
      (const __attribute__((address_space(1))) void*)g,
      (__attribute__((address_space(3))) void*)l, 16, 0, 0);
}

// all four weight tensors f32 -> bf16 in ONE launch.
// f32x4 segment sizes: conv 16384 | value 16384 | offset 7168 | out 16384
// total 56320 = 220 blocks * 256 threads exactly.
__global__ __launch_bounds__(256) void cast_all(
    const float* __restrict__ a0, u16* __restrict__ o0,
    const float* __restrict__ a1, u16* __restrict__ o1,
    const float* __restrict__ a2, u16* __restrict__ o2,
    const float* __restrict__ a3, u16* __restrict__ o3) {
  int i = blockIdx.x * 256 + threadIdx.x;
  const float* in; u16* out; int base;
  if (i < 16384)      { in = a0; out = o0; base = 0; }
  else if (i < 32768) { in = a1; out = o1; base = 16384; }
  else if (i < 39936) { in = a2; out = o2; base = 32768; }
  else                { in = a3; out = o3; base = 39936; }
  int j = i - base;
  f32x4 v = reinterpret_cast<const f32x4*>(in)[j];
  u32 lo = (u32)f2b(v[0]) | ((u32)f2b(v[1]) << 16);
  u32 hi = (u32)f2b(v[2]) | ((u32)f2b(v[3]) << 16);
  reinterpret_cast<u32*>(out)[2 * j]     = lo;
  reinterpret_cast<u32*>(out)[2 * j + 1] = hi;
}

// per batch z: in f32 (C, HW) -> out bf16 (HW, C)
// store phase widened: u32 channel-pair stores (half the instructions).
__global__ __launch_bounds__(256) void nchw_to_nhwc(const float* __restrict__ in,
                                                    u16* __restrict__ out) {
  __shared__ float tile[64][65];
  const int z = blockIdx.z;
  in  += (size_t)z * C_DIM * HW;
  out += (size_t)z * HW * C_DIM;
  const int p0 = blockIdx.x * 64;   // pixel tile
  const int c0 = blockIdx.y * 64;   // channel tile
  const int t = threadIdx.x;
  const int col = t & 63, rb = t >> 6;
#pragma unroll
  for (int i = 0; i < 16; ++i) {
    int row = rb + i * 4;           // channel within tile
    tile[row][col] = in[(size_t)(c0 + row) * HW + p0 + col];
  }
  __syncthreads();
  const int cp = t & 31, pb = t >> 5;
#pragma unroll
  for (int i = 0; i < 8; ++i) {
    int p = pb + i * 8;             // pixel within tile
    u32 pk = (u32)f2b(tile[2 * cp][p]) | ((u32)f2b(tile[2 * cp + 1][p]) << 16);
    *reinterpret_cast<u32*>(out + (size_t)(p0 + p) * C_DIM + c0 + 2 * cp) = pk;
  }
}

// ---------------------------------------------------------------------------
// GEMM: D[m,n] = epilogue( sum_k A[m,k]*B[n,k] ), async global_load_lds
// staging (m97 2-barrier structure), 128x128 tile, BK=32, 16x16x32 MFMA.
// MODE 0: bn+silu -> Cb bf16 (stride 256)
// MODE 1: fused value+offset: bn-tile<256 -> Cb bf16 +bias; else Cf f32 +bias2
// MODE 3: +bias,bn,silu -> Cf f32 NCHW DIRECT (acc f32x4 = 4 consecutive
//         pixels at one channel = one contiguous 16B NCHW span; kills the
//         separate nhwc_to_nchw_f32 pass: 192 MB traffic -> 128 MB).
// ---------------------------------------------------------------------------
template <int MODE>
__global__ __launch_bounds__(256) void gemm_ep(
    const u16* __restrict__ A, const u16* __restrict__ B,
    u16* __restrict__ Cb, float* __restrict__ Cf, int K, int Nreal,
    const float* __restrict__ bias, const float* __restrict__ bias2,
    const float* __restrict__ gamma, const float* __restrict__ beta,
    const float* __restrict__ mean, const float* __restrict__ var) {
  constexpr int BM = 128, BK = 32;
  __shared__ __align__(16) u16 As[BM * BK];
  __shared__ __align__(16) u16 Bs[BM * BK];
  const int tid  = threadIdx.x;
  const int lane = tid & 63;
  const int wave = tid >> 6;
  const int quad = lane >> 4;
  const int l16  = lane & 15;
  const int bm = blockIdx.x * BM;
  const int bn = blockIdx.y * BM;
  const int wm = (wave & 1) * 64;
  const int wn = (wave >> 1) * 64;

  f32x4 acc[4][4] = {};

  for (int ko = 0; ko < K; ko += BK) {
#pragma unroll
    for (int it = 0; it < 2; ++it) {
      int chunk = it * 256 + tid;          // 16B chunk id, 512 per tile
      int r  = chunk >> 2;                 // tile row 0..127
      int kk = (chunk & 3) << 3;           // k offset 0,8,16,24
      const u16* ga = A + (size_t)(bm + r) * K + (ko + kk);
      int br = bn + r; if (br >= Nreal) br = Nreal - 1;   // clamp (N=368 case)
      const u16* gb = B + (size_t)br * K + (ko + kk);
      u16* la = As + (size_t)(it * 256 + wave * 64) * 8;  // wave-uniform base
      u16* lb = Bs + (size_t)(it * 256 + wave * 64) * 8;
      async_cp16(ga, la);
      async_cp16(gb, lb);
    }
    __syncthreads();   // drains vmcnt (async copies) + prior ds_reads
    const bf16x8* Ap = reinterpret_cast<const bf16x8*>(As);
    const bf16x8* Bp = reinterpret_cast<const bf16x8*>(Bs);
    bf16x8 af[4], bfr[4];
#pragma unroll
    for (int mi = 0; mi < 4; ++mi) af[mi] = Ap[(wm + mi * 16 + l16) * 4 + quad];
#pragma unroll
    for (int ni = 0; ni < 4; ++ni) bfr[ni] = Bp[(wn + ni * 16 + l16) * 4 + quad];
#pragma unroll
    for (int mi = 0; mi < 4; ++mi)
#pragma unroll
      for (int ni = 0; ni < 4; ++ni)
        acc[mi][ni] = __builtin_amdgcn_mfma_f32_16x16x32_bf16(
            af[mi], bfr[ni], acc[mi][ni], 0, 0, 0);
    __syncthreads();
  }

#pragma unroll
  for (int ni = 0; ni < 4; ++ni) {
    int n = bn + wn + ni * 16 + l16;
    if constexpr (MODE == 0) {
      float sc = gamma[n] * rsqrtf(var[n] + EPSV);
      float sh = beta[n] - mean[n] * sc;
#pragma unroll
      for (int mi = 0; mi < 4; ++mi) {
        int mrow = bm + wm + mi * 16 + quad * 4;
#pragma unroll
        for (int i = 0; i < 4; ++i) {
          float y = acc[mi][ni][i] * sc + sh;
          y = y / (1.f + __expf(-y));   // silu
          Cb[(size_t)(mrow + i) * C_DIM + n] = f2b(y);
        }
      }
    } else if constexpr (MODE == 3) {  // bias+bn+silu -> f32 NCHW direct
      float sc = gamma[n] * rsqrtf(var[n] + EPSV);
      float sh = beta[n] - mean[n] * sc + bias[n] * sc;
#pragma unroll
      for (int mi = 0; mi < 4; ++mi) {
        int mrow = bm + wm + mi * 16 + quad * 4;
        int img = mrow >> 14;            // BM=128 divides HW -> uniform img
        int hw  = mrow & (HW - 1);
        f32x4 y;
#pragma unroll
        for (int i = 0; i < 4; ++i) {
          float z = acc[mi][ni][i] * sc + sh;
          y[i] = z / (1.f + __expf(-z));   // silu
        }
        *reinterpret_cast<f32x4*>(
            Cf + (size_t)img * C_DIM * HW + (size_t)n * HW + hw) = y;
      }
    } else {  // MODE 1: fused value(bf16) + offset(f32)
      if (bn < C_DIM) {
        float sh = bias[n];
#pragma unroll
        for (int mi = 0; mi < 4; ++mi) {
          int mrow = bm + wm + mi * 16 + quad * 4;
#pragma unroll
          for (int i = 0; i < 4; ++i)
            Cb[(size_t)(mrow + i) * C_DIM + n] = f2b(acc[mi][ni][i] + sh);
        }
      } else {
        int col = n - C_DIM;
        bool ok = col < PADOFF;
        float sh = ok ? bias2[col] : 0.f;
#pragma unroll
        for (int mi = 0; mi < 4; ++mi) {
          int mrow = bm + wm + mi * 16 + quad * 4;
#pragma unroll
          for (int i = 0; i < 4; ++i)
            if (ok) Cf[(size_t)(mrow + i) * PADOFF + col] = acc[mi][ni][i] + sh;
        }
      }
    }
  }
}

// ---------------------------------------------------------------------------
// Deformable sampling, v6 (proven r4: 40 VGPR, occ 50%, 52us):
// dot2-packed inner loop — v_perm pairs horizontal corners' bf16 channels,
// v_dot2_f32_bf16 applies both corner weights in one instr; weights packed
// via v_cvt_pk_bf16_f32; output packed via cvt_pk. XCD swizzle for L2.
// v: (M, C) NHWC bf16 ; om: (M, 112) f32 [per g: 18 offsets(x,y), 9 masks]
// ---------------------------------------------------------------------------
__global__ __launch_bounds__(256) void dcn_sample(
    const u16* __restrict__ v, const float* __restrict__ om,
    u16* __restrict__ outp) {
  __shared__ float sm[16 * PADOFF];   // 1792 f32 = 7 KiB
  const int tid = threadIdx.x;
  // XCD swizzle (gridDim.x = 4096, divisible by 8 -> bijective)
  const int bid = blockIdx.x;
  const int cpx = gridDim.x >> 3;               // blocks per XCD chunk
  const int wg  = (bid & 7) * cpx + (bid >> 3);
  const int m0  = wg * 16;
  {
    const float* src = om + (size_t)m0 * PADOFF;
#pragma unroll
    for (int i = 0; i < 7; ++i) sm[tid + i * 256] = src[tid + i * 256];
  }
  __syncthreads();
  const int c4 = tid & 3;            // 16-channel slice within group
  const int g  = (tid >> 2) & 3;
  const int pl = tid >> 4;           // pixel within block
  const int m  = m0 + pl;
  const int n  = m >> 14;            // HW = 2^14
  const int hw = m & (HW - 1);
  const int h = hw >> 7, w = hw & 127;
  const float* p = sm + pl * PADOFF + g * 27;
  const u16* vb = v + (size_t)n * HW * C_DIM + g * CG + c4 * 16;
  float acc[16] = {};
#pragma unroll
  for (int k = 0; k < 9; ++k) {
    const int di = k / 3 - 1, dj = k % 3 - 1;
    float ox = p[2 * k], oy = p[2 * k + 1], mk = p[18 + k];
    float lh = (float)(h + di) + oy;
    float lw = (float)(w + dj) + ox;
    float fh = floorf(lh), fw = floorf(lw);
    float dh = lh - fh, dw = lw - fw;
    int h0 = (int)fh, w0 = (int)fw;
    float wy0 = (1.f - dh) * mk, wy1 = dh * mk;
    float wx0 = 1.f - dw, wx1 = dw;
    bool okw0 = (u32)w0 < (u32)W_DIM;
    bool okw1 = (u32)(w0 + 1) < (u32)W_DIM;
    int w0c = min(max(w0, 0), W_DIM - 1);
    int w1c = min(max(w0 + 1, 0), W_DIM - 1);
#pragma unroll
    for (int cy = 0; cy < 2; ++cy) {
      int hh = h0 + cy;
      bool okh = (u32)hh < (u32)H_DIM;
      int hc = min(max(hh, 0), H_DIM - 1);
      const u16* rowp = vb + (size_t)(hc << 7) * C_DIM;
      const u16* qA = rowp + (size_t)w0c * C_DIM;
      const u16* qB = rowp + (size_t)w1c * C_DIM;
      u32x4 a0 = *reinterpret_cast<const u32x4*>(qA);
      u32x4 a1 = *reinterpret_cast<const u32x4*>(qA + 8);
      u32x4 b0 = *reinterpret_cast<const u32x4*>(qB);
      u32x4 b1 = *reinterpret_cast<const u32x4*>(qB + 8);
      float wyc = (cy == 0) ? wy0 : wy1;
      float wtA = (okh && okw0) ? wyc * wx0 : 0.f;
      float wtB = (okh && okw1) ? wyc * wx1 : 0.f;
      u32 wp;
      asm("v_cvt_pk_bf16_f32 %0, %1, %2" : "=v"(wp) : "v"(wtA), "v"(wtB));
#pragma unroll
      for (int j = 0; j < 4; ++j) {
        u32 lo0 = __builtin_amdgcn_perm(a0[j], b0[j], 0x01000504u);
        u32 hi0 = __builtin_amdgcn_perm(a0[j], b0[j], 0x03020706u);
        u32 lo1 = __builtin_amdgcn_perm(a1[j], b1[j], 0x01000504u);
        u32 hi1 = __builtin_amdgcn_perm(a1[j], b1[j], 0x03020706u);
        asm("v_dot2_f32_bf16 %0, %1, %2, %3"
            : "=v"(acc[2 * j]) : "v"(lo0), "v"(wp), "v"(acc[2 * j]));
        asm("v_dot2_f32_bf16 %0, %1, %2, %3"
            : "=v"(acc[2 * j + 1]) : "v"(hi0), "v"(wp), "v"(acc[2 * j + 1]));
        asm("v_dot2_f32_bf16 %0, %1, %2, %3"
            : "=v"(acc[8 + 2 * j]) : "v"(lo1), "v"(wp), "v"(acc[8 + 2 * j]));
        asm("v_dot2_f32_bf16 %0, %1, %2, %3"
            : "=v"(acc[8 + 2 * j + 1]) : "v"(hi1), "v"(wp), "v"(acc[8 + 2 * j + 1]));
      }
    }
  }
  u32x4 r0, r1;
#pragma unroll
  for (int j = 0; j < 4; ++j) {
    u32 pa, pb;
    asm("v_cvt_pk_bf16_f32 %0, %1, %2"
        : "=v"(pa) : "v"(acc[2 * j]), "v"(acc[2 * j + 1]));
    asm("v_cvt_pk_bf16_f32 %0, %1, %2"
        : "=v"(pb) : "v"(acc[8 + 2 * j]), "v"(acc[8 + 2 * j + 1]));
    r0[j] = pa; r1[j] = pb;
  }
  u16* o = outp + (size_t)m * C_DIM + g * CG + c4 * 16;
  *reinterpret_cast<u32x4*>(o)     = r0;
  *reinterpret_cast<u32x4*>(o + 8) = r1;
}

// ---------------------------------------------------------------------------
extern "C" void kernel_launch(void* const* d_in, const int* in_sizes, int n_in,
                              void* d_out, int out_size, void* d_ws, size_t ws_size,
                              hipStream_t stream) {
  const float* x        = (const float*)d_in[0];
  const float* conv_w   = (const float*)d_in[1];
  const float* bn1_g    = (const float*)d_in[2];
  const float* bn1_b    = (const float*)d_in[3];
  const float* bn1_m    = (const float*)d_in[4];
  const float* bn1_v    = (const float*)d_in[5];
  const float* value_w  = (const float*)d_in[6];
  const float* value_b  = (const float*)d_in[7];
  const float* offset_w = (const float*)d_in[8];
  const float* offset_b = (const float*)d_in[9];
  const float* out_w    = (const float*)d_in[10];
  const float* out_b    = (const float*)d_in[11];
  const float* bn2_g    = (const float*)d_in[12];
  const float* bn2_b    = (const float*)d_in[13];
  const float* bn2_m    = (const float*)d_in[14];
  const float* bn2_v    = (const float*)d_in[15];

  char* ws = (char*)d_ws;
  u16*   xt   = (u16*)(ws);                    // 32 MiB  (x NHWC bf16)
  u16*   t    = (u16*)(ws + 33554432);         // 32 MiB  (post conv+bn1+silu)
  u16*   vv   = (u16*)(ws + 67108864);         // 32 MiB  (value proj)
  float* om   = (float*)(ws + 100663296);      // 28 MiB  (offset+mask f32)
  u16*   wc   = (u16*)(ws + 130023424);        // conv_w bf16 (128 KiB)
  u16*   wcat = (u16*)(ws + 130154496);        // [value_w; offset_w] bf16 (368x256)
  u16*   wout = (u16*)(ws + 130342912);        // out_w bf16 (128 KiB)
  u16*   dcn  = xt;                            // reuse (xt dead after K1)
  float* outp = (float*)d_out;                 // final output is f32

  // W: all weights f32 -> bf16 in one launch (value+offset concatenated)
  cast_all<<<220, 256, 0, stream>>>(conv_w, wc, value_w, wcat,
                                    offset_w, wcat + 65536, out_w, wout);

  // K0: x f32 NCHW -> bf16 NHWC
  nchw_to_nhwc<<<dim3(HW / 64, C_DIM / 64, N_IMG), 256, 0, stream>>>(x, xt);
  // K1: t = silu(bn1(xt @ conv_w^T))
  gemm_ep<0><<<dim3(M_TOT / 128, 2), 256, 0, stream>>>(
      xt, wc, t, nullptr, C_DIM, C_DIM,
      nullptr, nullptr, bn1_g, bn1_b, bn1_m, bn1_v);
  // K2: fused [vv | om] = t @ [value_w; offset_w]^T + [value_b; offset_b]
  gemm_ep<1><<<dim3(M_TOT / 128, 3), 256, 0, stream>>>(
      t, wcat, vv, om, C_DIM, C_DIM + PADOFF,
      value_b, offset_b, nullptr, nullptr, nullptr, nullptr);
  // K4: deformable bilinear sampling (16 px / block)
  dcn_sample<<<dim3(M_TOT / 16), 256, 0, stream>>>(vv, om, dcn);
  // K5: d_out = silu(bn2(dcn @ out_w^T + out_b))  f32 NCHW DIRECT (was K5+K6)
  gemm_ep<3><<<dim3(M_TOT / 128, 2), 256, 0, stream>>>(
      dcn, wout, nullptr, outp, C_DIM, C_DIM,
      out_b, nullptr, bn2_g, bn2_b, bn2_m, bn2_v);
}

// Round 7
// 278.745 us; speedup vs baseline: 1.2978x; 1.0212x over previous
//
#include <hip/hip_runtime.h>
#include <cstdint>

typedef unsigned short u16;   // bf16 bit pattern
typedef unsigned int   u32;
typedef __attribute__((ext_vector_type(8))) __bf16 bf16x8;
typedef __attribute__((ext_vector_type(4))) float  f32x4;
typedef __attribute__((ext_vector_type(4))) u32    u32x4;

#define N_IMG 4
#define C_DIM 256
#define H_DIM 128
#define W_DIM 128
#define HW    (H_DIM * W_DIM)      // 16384
#define M_TOT (N_IMG * HW)         // 65536
#define CG    64
#define PADOFF 112
#define EPSV  1e-5f

__device__ __forceinline__ u16 f2b(float f) {
  u32 u = __float_as_uint(f);
  u += 0x7fffu + ((u >> 16) & 1u);   // round-to-nearest-even
  return (u16)(u >> 16);
}

// async global->LDS, 16B per lane; LDS dest = wave-uniform base + lane*16
__device__ __forceinline__ void async_cp16(const void* g, void* l) {
  __builtin_amdgcn_global_load_lds(
      (const __attribute__((address_space(1))) void*)g,
      (__attribute__((address_space(3))) void*)l, 16, 0, 0);
}

// all four weight tensors f32 -> bf16 in ONE launch.
// f32x4 segment sizes: conv 16384 | value 16384 | offset 7168 | out 16384
// total 56320 = 220 blocks * 256 threads exactly.
__global__ __launch_bounds__(256) void cast_all(
    const float* __restrict__ a0, u16* __restrict__ o0,
    const float* __restrict__ a1, u16* __restrict__ o1,
    const float* __restrict__ a2, u16* __restrict__ o2,
    const float* __restrict__ a3, u16* __restrict__ o3) {
  int i = blockIdx.x * 256 + threadIdx.x;
  const float* in; u16* out; int base;
  if (i < 16384)      { in = a0; out = o0; base = 0; }
  else if (i < 32768) { in = a1; out = o1; base = 16384; }
  else if (i < 39936) { in = a2; out = o2; base = 32768; }
  else                { in = a3; out = o3; base = 39936; }
  int j = i - base;
  f32x4 v = reinterpret_cast<const f32x4*>(in)[j];
  u32 lo = (u32)f2b(v[0]) | ((u32)f2b(v[1]) << 16);
  u32 hi = (u32)f2b(v[2]) | ((u32)f2b(v[3]) << 16);
  reinterpret_cast<u32*>(out)[2 * j]     = lo;
  reinterpret_cast<u32*>(out)[2 * j + 1] = hi;
}

// per batch z: in f32 (C, HW) -> out bf16 (HW, C)
__global__ __launch_bounds__(256) void nchw_to_nhwc(const float* __restrict__ in,
                                                    u16* __restrict__ out) {
  __shared__ float tile[64][65];
  const int z = blockIdx.z;
  in  += (size_t)z * C_DIM * HW;
  out += (size_t)z * HW * C_DIM;
  const int p0 = blockIdx.x * 64;   // pixel tile
  const int c0 = blockIdx.y * 64;   // channel tile
  const int t = threadIdx.x;
  const int col = t & 63, rb = t >> 6;
#pragma unroll
  for (int i = 0; i < 16; ++i) {
    int row = rb + i * 4;           // channel within tile
    tile[row][col] = in[(size_t)(c0 + row) * HW + p0 + col];
  }
  __syncthreads();
  const int cp = t & 31, pb = t >> 5;
#pragma unroll
  for (int i = 0; i < 8; ++i) {
    int p = pb + i * 8;             // pixel within tile
    u32 pk = (u32)f2b(tile[2 * cp][p]) | ((u32)f2b(tile[2 * cp + 1][p]) << 16);
    *reinterpret_cast<u32*>(out + (size_t)(p0 + p) * C_DIM + c0 + 2 * cp) = pk;
  }
}

// ---------------------------------------------------------------------------
// GEMM: D[m,n] = epilogue( sum_k A[m,k]*B[n,k] ), async global_load_lds
// staging, 128x128 tile, 16x16x32 MFMA.
// BK=64: halves the per-K-step vmcnt(0) drains (8 -> 4 at K=256). Wider LDS
// row (128 B) would be a 16-way bank conflict on ds_read_b128, so staging
// applies a both-sides XOR swizzle (rule #21): global SOURCE k-chunk j^(r&7)
// at stage time, same XOR on the read index -> restores the 8-way parity of
// the proven BK=32 layout. Pure permutation of staging -> accumulation order
// unchanged (bit-identical output vs BK=32).
// MODE 0: bn+silu -> Cb bf16 (stride 256)
// MODE 1: fused value+offset: bn-tile<256 -> Cb bf16 +bias; else Cf f32 +bias2
// MODE 3: +bias,bn,silu -> Cf f32 NCHW DIRECT
// ---------------------------------------------------------------------------
template <int MODE>
__global__ __launch_bounds__(256) void gemm_ep(
    const u16* __restrict__ A, const u16* __restrict__ B,
    u16* __restrict__ Cb, float* __restrict__ Cf, int K, int Nreal,
    const float* __restrict__ bias, const float* __restrict__ bias2,
    const float* __restrict__ gamma, const float* __restrict__ beta,
    const float* __restrict__ mean, const float* __restrict__ var) {
  constexpr int BM = 128, BK = 64;
  __shared__ __align__(16) u16 As[BM * BK];   // 16 KiB
  __shared__ __align__(16) u16 Bs[BM * BK];   // 16 KiB
  const int tid  = threadIdx.x;
  const int lane = tid & 63;
  const int wave = tid >> 6;
  const int quad = lane >> 4;
  const int l16  = lane & 15;
  const int bm = blockIdx.x * BM;
  const int bn = blockIdx.y * BM;
  const int wm = (wave & 1) * 64;
  const int wn = (wave >> 1) * 64;

  f32x4 acc[4][4] = {};

  for (int ko = 0; ko < K; ko += BK) {
#pragma unroll
    for (int it = 0; it < 4; ++it) {
      int chunk = it * 256 + tid;          // 16B chunk id, 1024 per tile
      int r  = chunk >> 3;                 // tile row 0..127
      int j  = chunk & 7;                  // k-chunk slot 0..7
      int kk = (j ^ (r & 7)) << 3;         // swizzled global k offset
      const u16* ga = A + (size_t)(bm + r) * K + (ko + kk);
      int br = bn + r; if (br >= Nreal) br = Nreal - 1;   // clamp (N=368 case)
      const u16* gb = B + (size_t)br * K + (ko + kk);
      u16* la = As + (size_t)(it * 256 + wave * 64) * 8;  // wave-uniform base
      u16* lb = Bs + (size_t)(it * 256 + wave * 64) * 8;
      async_cp16(ga, la);
      async_cp16(gb, lb);
    }
    __syncthreads();   // drains vmcnt (async copies) + prior ds_reads
    const bf16x8* Ap = reinterpret_cast<const bf16x8*>(As);
    const bf16x8* Bp = reinterpret_cast<const bf16x8*>(Bs);
#pragma unroll
    for (int ks = 0; ks < 2; ++ks) {
      bf16x8 af[4], bfr[4];
#pragma unroll
      for (int mi = 0; mi < 4; ++mi) {
        int row = wm + mi * 16 + l16;
        af[mi] = Ap[row * 8 + ((ks * 4 + quad) ^ (row & 7))];
      }
#pragma unroll
      for (int ni = 0; ni < 4; ++ni) {
        int row = wn + ni * 16 + l16;
        bfr[ni] = Bp[row * 8 + ((ks * 4 + quad) ^ (row & 7))];
      }
#pragma unroll
      for (int mi = 0; mi < 4; ++mi)
#pragma unroll
        for (int ni = 0; ni < 4; ++ni)
          acc[mi][ni] = __builtin_amdgcn_mfma_f32_16x16x32_bf16(
              af[mi], bfr[ni], acc[mi][ni], 0, 0, 0);
    }
    __syncthreads();
  }

#pragma unroll
  for (int ni = 0; ni < 4; ++ni) {
    int n = bn + wn + ni * 16 + l16;
    if constexpr (MODE == 0) {
      float sc = gamma[n] * rsqrtf(var[n] + EPSV);
      float sh = beta[n] - mean[n] * sc;
#pragma unroll
      for (int mi = 0; mi < 4; ++mi) {
        int mrow = bm + wm + mi * 16 + quad * 4;
#pragma unroll
        for (int i = 0; i < 4; ++i) {
          float y = acc[mi][ni][i] * sc + sh;
          y = y / (1.f + __expf(-y));   // silu
          Cb[(size_t)(mrow + i) * C_DIM + n] = f2b(y);
        }
      }
    } else if constexpr (MODE == 3) {  // bias+bn+silu -> f32 NCHW direct
      float sc = gamma[n] * rsqrtf(var[n] + EPSV);
      float sh = beta[n] - mean[n] * sc + bias[n] * sc;
#pragma unroll
      for (int mi = 0; mi < 4; ++mi) {
        int mrow = bm + wm + mi * 16 + quad * 4;
        int img = mrow >> 14;            // BM=128 divides HW -> uniform img
        int hw  = mrow & (HW - 1);
        f32x4 y;
#pragma unroll
        for (int i = 0; i < 4; ++i) {
          float z = acc[mi][ni][i] * sc + sh;
          y[i] = z / (1.f + __expf(-z));   // silu
        }
        *reinterpret_cast<f32x4*>(
            Cf + (size_t)img * C_DIM * HW + (size_t)n * HW + hw) = y;
      }
    } else {  // MODE 1: fused value(bf16) + offset(f32)
      if (bn < C_DIM) {
        float sh = bias[n];
#pragma unroll
        for (int mi = 0; mi < 4; ++mi) {
          int mrow = bm + wm + mi * 16 + quad * 4;
#pragma unroll
          for (int i = 0; i < 4; ++i)
            Cb[(size_t)(mrow + i) * C_DIM + n] = f2b(acc[mi][ni][i] + sh);
        }
      } else {
        int col = n - C_DIM;
        bool ok = col < PADOFF;
        float sh = ok ? bias2[col] : 0.f;
#pragma unroll
        for (int mi = 0; mi < 4; ++mi) {
          int mrow = bm + wm + mi * 16 + quad * 4;
#pragma unroll
          for (int i = 0; i < 4; ++i)
            if (ok) Cf[(size_t)(mrow + i) * PADOFF + col] = acc[mi][ni][i] + sh;
        }
      }
    }
  }
}

// ---------------------------------------------------------------------------
// Deformable sampling, v6 (proven r4: 40 VGPR, occ 50%, ~51us):
// dot2-packed inner loop — v_perm pairs horizontal corners' bf16 channels,
// v_dot2_f32_bf16 applies both corner weights in one instr; weights packed
// via v_cvt_pk_bf16_f32; output packed via cvt_pk. XCD swizzle for L2.
// v: (M, C) NHWC bf16 ; om: (M, 112) f32 [per g: 18 offsets(x,y), 9 masks]
// ---------------------------------------------------------------------------
__global__ __launch_bounds__(256) void dcn_sample(
    const u16* __restrict__ v, const float* __restrict__ om,
    u16* __restrict__ outp) {
  __shared__ float sm[16 * PADOFF];   // 1792 f32 = 7 KiB
  const int tid = threadIdx.x;
  // XCD swizzle (gridDim.x = 4096, divisible by 8 -> bijective)
  const int bid = blockIdx.x;
  const int cpx = gridDim.x >> 3;               // blocks per XCD chunk
  const int wg  = (bid & 7) * cpx + (bid >> 3);
  const int m0  = wg * 16;
  {
    const float* src = om + (size_t)m0 * PADOFF;
#pragma unroll
    for (int i = 0; i < 7; ++i) sm[tid + i * 256] = src[tid + i * 256];
  }
  __syncthreads();
  const int c4 = tid & 3;            // 16-channel slice within group
  const int g  = (tid >> 2) & 3;
  const int pl = tid >> 4;           // pixel within block
  const int m  = m0 + pl;
  const int n  = m >> 14;            // HW = 2^14
  const int hw = m & (HW - 1);
  const int h = hw >> 7, w = hw & 127;
  const float* p = sm + pl * PADOFF + g * 27;
  const u16* vb = v + (size_t)n * HW * C_DIM + g * CG + c4 * 16;
  float acc[16] = {};
#pragma unroll
  for (int k = 0; k < 9; ++k) {
    const int di = k / 3 - 1, dj = k % 3 - 1;
    float ox = p[2 * k], oy = p[2 * k + 1], mk = p[18 + k];
    float lh = (float)(h + di) + oy;
    float lw = (float)(w + dj) + ox;
    float fh = floorf(lh), fw = floorf(lw);
    float dh = lh - fh, dw = lw - fw;
    int h0 = (int)fh, w0 = (int)fw;
    float wy0 = (1.f - dh) * mk, wy1 = dh * mk;
    float wx0 = 1.f - dw, wx1 = dw;
    bool okw0 = (u32)w0 < (u32)W_DIM;
    bool okw1 = (u32)(w0 + 1) < (u32)W_DIM;
    int w0c = min(max(w0, 0), W_DIM - 1);
    int w1c = min(max(w0 + 1, 0), W_DIM - 1);
#pragma unroll
    for (int cy = 0; cy < 2; ++cy) {
      int hh = h0 + cy;
      bool okh = (u32)hh < (u32)H_DIM;
      int hc = min(max(hh, 0), H_DIM - 1);
      const u16* rowp = vb + (size_t)(hc << 7) * C_DIM;
      const u16* qA = rowp + (size_t)w0c * C_DIM;
      const u16* qB = rowp + (size_t)w1c * C_DIM;
      u32x4 a0 = *reinterpret_cast<const u32x4*>(qA);
      u32x4 a1 = *reinterpret_cast<const u32x4*>(qA + 8);
      u32x4 b0 = *reinterpret_cast<const u32x4*>(qB);
      u32x4 b1 = *reinterpret_cast<const u32x4*>(qB + 8);
      float wyc = (cy == 0) ? wy0 : wy1;
      float wtA = (okh && okw0) ? wyc * wx0 : 0.f;
      float wtB = (okh && okw1) ? wyc * wx1 : 0.f;
      u32 wp;
      asm("v_cvt_pk_bf16_f32 %0, %1, %2" : "=v"(wp) : "v"(wtA), "v"(wtB));
#pragma unroll
      for (int j = 0; j < 4; ++j) {
        u32 lo0 = __builtin_amdgcn_perm(a0[j], b0[j], 0x01000504u);
        u32 hi0 = __builtin_amdgcn_perm(a0[j], b0[j], 0x03020706u);
        u32 lo1 = __builtin_amdgcn_perm(a1[j], b1[j], 0x01000504u);
        u32 hi1 = __builtin_amdgcn_perm(a1[j], b1[j], 0x03020706u);
        asm("v_dot2_f32_bf16 %0, %1, %2, %3"
            : "=v"(acc[2 * j]) : "v"(lo0), "v"(wp), "v"(acc[2 * j]));
        asm("v_dot2_f32_bf16 %0, %1, %2, %3"
            : "=v"(acc[2 * j + 1]) : "v"(hi0), "v"(wp), "v"(acc[2 * j + 1]));
        asm("v_dot2_f32_bf16 %0, %1, %2, %3"
            : "=v"(acc[8 + 2 * j]) : "v"(lo1), "v"(wp), "v"(acc[8 + 2 * j]));
        asm("v_dot2_f32_bf16 %0, %1, %2, %3"
            : "=v"(acc[8 + 2 * j + 1]) : "v"(hi1), "v"(wp), "v"(acc[8 + 2 * j + 1]));
      }
    }
  }
  u32x4 r0, r1;
#pragma unroll
  for (int j = 0; j < 4; ++j) {
    u32 pa, pb;
    asm("v_cvt_pk_bf16_f32 %0, %1, %2"
        : "=v"(pa) : "v"(acc[2 * j]), "v"(acc[2 * j + 1]));
    asm("v_cvt_pk_bf16_f32 %0, %1, %2"
        : "=v"(pb) : "v"(acc[8 + 2 * j]), "v"(acc[8 + 2 * j + 1]));
    r0[j] = pa; r1[j] = pb;
  }
  u16* o = outp + (size_t)m * C_DIM + g * CG + c4 * 16;
  *reinterpret_cast<u32x4*>(o)     = r0;
  *reinterpret_cast<u32x4*>(o + 8) = r1;
}

// ---------------------------------------------------------------------------
extern "C" void kernel_launch(void* const* d_in, const int* in_sizes, int n_in,
                              void* d_out, int out_size, void* d_ws, size_t ws_size,
                              hipStream_t stream) {
  const float* x        = (const float*)d_in[0];
  const float* conv_w   = (const float*)d_in[1];
  const float* bn1_g    = (const float*)d_in[2];
  const float* bn1_b    = (const float*)d_in[3];
  const float* bn1_m    = (const float*)d_in[4];
  const float* bn1_v    = (const float*)d_in[5];
  const float* value_w  = (const float*)d_in[6];
  const float* value_b  = (const float*)d_in[7];
  const float* offset_w = (const float*)d_in[8];
  const float* offset_b = (const float*)d_in[9];
  const float* out_w    = (const float*)d_in[10];
  const float* out_b    = (const float*)d_in[11];
  const float* bn2_g    = (const float*)d_in[12];
  const float* bn2_b    = (const float*)d_in[13];
  const float* bn2_m    = (const float*)d_in[14];
  const float* bn2_v    = (const float*)d_in[15];

  char* ws = (char*)d_ws;
  u16*   xt   = (u16*)(ws);                    // 32 MiB  (x NHWC bf16)
  u16*   t    = (u16*)(ws + 33554432);         // 32 MiB  (post conv+bn1+silu)
  u16*   vv   = (u16*)(ws + 67108864);         // 32 MiB  (value proj)
  float* om   = (float*)(ws + 100663296);      // 28 MiB  (offset+mask f32)
  u16*   wc   = (u16*)(ws + 130023424);        // conv_w bf16 (128 KiB)
  u16*   wcat = (u16*)(ws + 130154496);        // [value_w; offset_w] bf16 (368x256)
  u16*   wout = (u16*)(ws + 130342912);        // out_w bf16 (128 KiB)
  u16*   dcn  = xt;                            // reuse (xt dead after K1)
  float* outp = (float*)d_out;                 // final output is f32

  // W: all weights f32 -> bf16 in one launch (value+offset concatenated)
  cast_all<<<220, 256, 0, stream>>>(conv_w, wc, value_w, wcat,
                                    offset_w, wcat + 65536, out_w, wout);

  // K0: x f32 NCHW -> bf16 NHWC
  nchw_to_nhwc<<<dim3(HW / 64, C_DIM / 64, N_IMG), 256, 0, stream>>>(x, xt);
  // K1: t = silu(bn1(xt @ conv_w^T))
  gemm_ep<0><<<dim3(M_TOT / 128, 2), 256, 0, stream>>>(
      xt, wc, t, nullptr, C_DIM, C_DIM,
      nullptr, nullptr, bn1_g, bn1_b, bn1_m, bn1_v);
  // K2: fused [vv | om] = t @ [value_w; offset_w]^T + [value_b; offset_b]
  gemm_ep<1><<<dim3(M_TOT / 128, 3), 256, 0, stream>>>(
      t, wcat, vv, om, C_DIM, C_DIM + PADOFF,
      value_b, offset_b, nullptr, nullptr, nullptr, nullptr);
  // K4: deformable bilinear sampling (16 px / block)
  dcn_sample<<<dim3(M_TOT / 16), 256, 0, stream>>>(vv, om, dcn);
  // K5: d_out = silu(bn2(dcn @ out_w^T + out_b))  f32 NCHW DIRECT
  gemm_ep<3><<<dim3(M_TOT / 128, 2), 256, 0, stream>>>(
      dcn, wout, nullptr, outp, C_DIM, C_DIM,
      out_b, nullptr, bn2_g, bn2_b, bn2_m, bn2_v);
}